// Round 7
// baseline (536.602 us; speedup 1.0000x reference)
//
#include <hip/hip_runtime.h>
#include <hip/hip_bf16.h>

#define NA 8192
#define NP 65536
#define WROW 1920

typedef short short8 __attribute__((ext_vector_type(8)));
typedef float floatx4 __attribute__((ext_vector_type(4)));

static __device__ __forceinline__ short f2bf(float f) {
    union { float f; unsigned u; } v; v.f = f;
    unsigned r = v.u + 0x7FFF + ((v.u >> 16) & 1);
    return (short)(r >> 16);
}
static __device__ __forceinline__ float bf2f(short s) {
    union { unsigned u; float f; } v;
    v.u = ((unsigned)(unsigned short)s) << 16;
    return v.f;
}
static __device__ __forceinline__ unsigned char f2fp8(float f) {
    int p = __builtin_amdgcn_cvt_pk_fp8_f32(f, 0.f, 0, false);
    return (unsigned char)(p & 0xFF);
}
static __device__ __forceinline__ float fp82f(unsigned char b) {
    return __builtin_amdgcn_cvt_f32_fp8((int)b, 0);
}
static __device__ __forceinline__ float silu(float v) {
    return v / (1.f + __expf(-v));
}

// ---------------- weight transpose + bf16 convert: Wt[b][n][k] = W[b][k][n] ----------------
__global__ __launch_bounds__(256) void k_tconv(const float* __restrict__ W,
                                               short* __restrict__ Wt,
                                               int K, int N, int total) {
    int idx = blockIdx.x * 256 + threadIdx.x;
    if (idx >= total) return;
    int kn = K * N;
    int b = idx / kn;
    int rem = idx - b * kn;
    int k = rem / N;
    int n = rem - k * N;
    Wt[b * kn + n * K + k] = f2bf(W[idx]);
}

// fWt[b][n][k] (k padded 20->32): from fW[k][b*384+n]
__global__ __launch_bounds__(256) void k_tconv2(const float* __restrict__ fW,
                                                short* __restrict__ fWt) {
    int idx = blockIdx.x * 256 + threadIdx.x;   // 0..5*384*32-1
    if (idx >= 5 * 384 * 32) return;
    int b = idx / 12288;
    int rem = idx - b * 12288;
    int n = rem >> 5, k = rem & 31;
    fWt[idx] = (k < 20) ? f2bf(fW[k * WROW + b * 384 + n]) : (short)0;
}

// ---------------- init ----------------
__global__ __launch_bounds__(256) void k_init(const float* __restrict__ feat,
                                              float* __restrict__ q,
                                              float* __restrict__ mu,
                                              short* __restrict__ q_bf,
                                              short* __restrict__ mu_bfA,
                                              int* __restrict__ counts,
                                              int* __restrict__ cursor) {
    int idx = blockIdx.x * 256 + threadIdx.x;     // 0 .. NA*384-1
    if (idx < NA * 128) { float v = feat[idx]; q[idx] = v; q_bf[idx] = f2bf(v); }
    mu[idx] = 0.f;
    mu_bfA[idx] = 0;
    if (idx < NA) { counts[idx] = 0; cursor[idx] = 0; }
}

// ---------------- CSR build ----------------
__global__ __launch_bounds__(256) void k_hist(const int* __restrict__ idx_i,
                                              int* __restrict__ counts) {
    int p = blockIdx.x * 256 + threadIdx.x;
    if (p < NP) atomicAdd(&counts[idx_i[p]], 1);
}

__global__ __launch_bounds__(1024) void k_scan(const int* __restrict__ counts,
                                               int* __restrict__ offs) {
    __shared__ int sums[1024];
    int t = threadIdx.x;
    int local[8];
    int s = 0;
    #pragma unroll
    for (int k = 0; k < 8; ++k) { local[k] = s; s += counts[t * 8 + k]; }
    sums[t] = s;
    __syncthreads();
    for (int off = 1; off < 1024; off <<= 1) {
        int v = sums[t];
        int u = (t >= off) ? sums[t - off] : 0;
        __syncthreads();
        sums[t] = v + u;
        __syncthreads();
    }
    int base = (t > 0) ? sums[t - 1] : 0;
    #pragma unroll
    for (int k = 0; k < 8; ++k) offs[t * 8 + k] = base + local[k];
    if (t == 1023) offs[NA] = sums[1023];
}

__global__ __launch_bounds__(256) void k_fill(const int* __restrict__ idx_i,
                                              const int* __restrict__ offs,
                                              int* __restrict__ cursor,
                                              int* __restrict__ plist) {
    int p = blockIdx.x * 256 + threadIdx.x;
    if (p < NP) {
        int i = idx_i[p];
        int pos = atomicAdd(&cursor[i], 1);
        plist[offs[i] + pos] = p;
    }
}

// ---------------- prep: pre-gather per-pair data into CSR order ----------------
__global__ __launch_bounds__(256) void k_prep(const int* __restrict__ plist,
                                              const int* __restrict__ idx_j,
                                              const float* __restrict__ cut,
                                              const float* __restrict__ dist,
                                              const float* __restrict__ vec,
                                              const float* __restrict__ rbfs,
                                              int* __restrict__ jcsr,
                                              float* __restrict__ cut_csr,
                                              float4* __restrict__ dir_csr,
                                              short* __restrict__ rbf_c) {
    int e = blockIdx.x * 256 + threadIdx.x;
    if (e >= NP) {                       // zero-pad 16 extra rows for tile overrun
        if (e < NP + 16) {
            cut_csr[e] = 0.f;
            #pragma unroll
            for (int k = 0; k < 32; ++k) rbf_c[e * 32 + k] = 0;
        }
        return;
    }
    int p = plist[e];
    jcsr[e] = idx_j[p];
    float c = cut[p];
    cut_csr[e] = c;
    float invd = 1.f / dist[p];
    float4 d;
    d.x = vec[p * 3 + 0] * invd;
    d.y = vec[p * 3 + 1] * invd;
    d.z = vec[p * 3 + 2] * invd;
    d.w = 0.f;
    dir_csr[e] = d;
    #pragma unroll
    for (int k = 0; k < 20; ++k) rbf_c[e * 32 + k] = f2bf(rbfs[p * 20 + k] * c);
    #pragma unroll
    for (int k = 20; k < 32; ++k) rbf_c[e * 32 + k] = 0;
}

// ---------------- K1 (MFMA): x = silu(q@W1+b1)@W2+b2, fp8 out (block 0 only) ----------------
__global__ __launch_bounds__(256) void k_x(const short* __restrict__ q_bf,
                                           const short* __restrict__ W1t,  // [128][128]
                                           const short* __restrict__ W2t,  // [384][128]
                                           const float* __restrict__ b1,
                                           const float* __restrict__ b2,
                                           unsigned char* __restrict__ x_fp8) {
    __shared__ __align__(16) short hs[16 * 128];
    int t = threadIdx.x;
    int wv = t >> 6, lane = t & 63, quad = lane >> 4, l16 = lane & 15;
    int a0 = blockIdx.x * 16;

    floatx4 acc0 = {0.f, 0.f, 0.f, 0.f}, acc1 = {0.f, 0.f, 0.f, 0.f};
    #pragma unroll
    for (int kk = 0; kk < 4; ++kk) {
        short8 a  = *(const short8*)(q_bf + (a0 + l16) * 128 + kk * 32 + quad * 8);
        short8 b0 = *(const short8*)(W1t + (wv * 32 + l16) * 128 + kk * 32 + quad * 8);
        short8 bq = *(const short8*)(W1t + (wv * 32 + 16 + l16) * 128 + kk * 32 + quad * 8);
        acc0 = __builtin_amdgcn_mfma_f32_16x16x32_bf16(a, b0, acc0, 0, 0, 0);
        acc1 = __builtin_amdgcn_mfma_f32_16x16x32_bf16(a, bq, acc1, 0, 0, 0);
    }
    {
        int n0 = wv * 32 + l16;
        float bia0 = b1[n0], bia1 = b1[n0 + 16];
        #pragma unroll
        for (int r = 0; r < 4; ++r) {
            int m = quad * 4 + r;
            hs[m * 128 + n0]      = f2bf(silu(acc0[r] + bia0));
            hs[m * 128 + n0 + 16] = f2bf(silu(acc1[r] + bia1));
        }
    }
    __syncthreads();
    floatx4 acc[6];
    #pragma unroll
    for (int jj = 0; jj < 6; ++jj) acc[jj] = {0.f, 0.f, 0.f, 0.f};
    #pragma unroll
    for (int kk = 0; kk < 4; ++kk) {
        short8 a = *(const short8*)(hs + l16 * 128 + kk * 32 + quad * 8);
        #pragma unroll
        for (int jj = 0; jj < 6; ++jj) {
            short8 b = *(const short8*)(W2t + (wv * 96 + jj * 16 + l16) * 128 + kk * 32 + quad * 8);
            acc[jj] = __builtin_amdgcn_mfma_f32_16x16x32_bf16(a, b, acc[jj], 0, 0, 0);
        }
    }
    #pragma unroll
    for (int jj = 0; jj < 6; ++jj) {
        int n = wv * 96 + jj * 16 + l16;
        float bia = b2[n];
        #pragma unroll
        for (int r = 0; r < 4; ++r) {
            int m = quad * 4 + r;
            x_fp8[(a0 + m) * 384 + n] = f2fp8(acc[jj][r] + bia);
        }
    }
}

// ---------------- K2: per-atom gather, 256 threads (two halves on even/odd pairs) ----------------
// Phase 1: desc tile via MFMA across 4 waves (6 N-tiles each) -> LDS bf16.
// Phase 2: half h (t>>7) walks pairs e0+h, e0+h+2, ... ; partials merged via LDS.
__global__ __launch_bounds__(256, 6) void k_gather(const unsigned char* __restrict__ x_fp8,
                                                   const short* __restrict__ mu_bfA,
                                                   const short* __restrict__ rbf_c,
                                                   const short* __restrict__ fWt,   // [384][32], block slice
                                                   const float* __restrict__ fbp,   // fb + bo
                                                   const int* __restrict__ jcsr,
                                                   const float* __restrict__ cut_csr,
                                                   const float4* __restrict__ dir_csr,
                                                   const int* __restrict__ offs,
                                                   float* __restrict__ q,
                                                   float* __restrict__ mu,
                                                   short* __restrict__ q_bf,
                                                   short* __restrict__ mu_bfB) {
    __shared__ short dlds[16 * 392];
    __shared__ float pm[4 * 128];
    int i = blockIdx.x;
    int t = threadIdx.x;
    int h = t >> 7;                             // pair-parity half
    int f = t & 127;                            // feature column
    int wv = t >> 6, lane = t & 63, quad = lane >> 4, l16 = lane & 15;
    int start = offs[i], end = offs[i + 1];
    float qa = 0.f, m0a = 0.f, m1a = 0.f, m2a = 0.f;

    for (int e0 = start; e0 < end; e0 += 16) {
        if (e0 > start) __syncthreads();        // protect dlds reuse
        // ---- phase 1: descriptors for rows e0..e0+15, 4 waves x 96 cols
        short8 a = *(const short8*)(rbf_c + (e0 + l16) * 32 + quad * 8);
        float c0 = cut_csr[e0 + quad * 4 + 0];
        float c1 = cut_csr[e0 + quad * 4 + 1];
        float c2 = cut_csr[e0 + quad * 4 + 2];
        float c3 = cut_csr[e0 + quad * 4 + 3];
        #pragma unroll
        for (int nt = 0; nt < 6; ++nt) {
            int col = wv * 96 + nt * 16 + l16;
            short8 bfr = *(const short8*)(fWt + col * 32 + quad * 8);
            floatx4 z = {0.f, 0.f, 0.f, 0.f};
            floatx4 acc = __builtin_amdgcn_mfma_f32_16x16x32_bf16(a, bfr, z, 0, 0, 0);
            float fbv = fbp[col];
            dlds[(quad * 4 + 0) * 392 + col] = f2bf(acc[0] + fbv * c0);
            dlds[(quad * 4 + 1) * 392 + col] = f2bf(acc[1] + fbv * c1);
            dlds[(quad * 4 + 2) * 392 + col] = f2bf(acc[2] + fbv * c2);
            dlds[(quad * 4 + 3) * 392 + col] = f2bf(acc[3] + fbv * c3);
        }
        __syncthreads();
        // ---- phase 2: this half walks its parity of pairs, depth-1 prefetch
        int lim = (end < e0 + 16) ? end : (e0 + 16);
        int e = e0 + h;
        if (e < lim) {
            int jA = jcsr[e];
            float4 dirA = dir_csr[e];
            unsigned char aX0 = x_fp8[jA * 384 + f];
            unsigned char aX1 = x_fp8[jA * 384 + 128 + f];
            unsigned char aX2 = x_fp8[jA * 384 + 256 + f];
            short aU0 = mu_bfA[jA * 384 + f];
            short aU1 = mu_bfA[jA * 384 + 128 + f];
            short aU2 = mu_bfA[jA * 384 + 256 + f];
            for (; e < lim; e += 2) {
                float x0 = fp82f(aX0), x1 = fp82f(aX1), x2 = fp82f(aX2);
                float u0 = bf2f(aU0), u1 = bf2f(aU1), u2 = bf2f(aU2);
                float4 cdir = dirA;
                int en = e + 2;
                if (en < lim) {
                    int jn = jcsr[en];
                    dirA = dir_csr[en];
                    aX0 = x_fp8[jn * 384 + f];
                    aX1 = x_fp8[jn * 384 + 128 + f];
                    aX2 = x_fp8[jn * 384 + 256 + f];
                    aU0 = mu_bfA[jn * 384 + f];
                    aU1 = mu_bfA[jn * 384 + 128 + f];
                    aU2 = mu_bfA[jn * 384 + 256 + f];
                }
                int le = e - e0;
                float wa = bf2f(dlds[le * 392 + f]);
                float wb = bf2f(dlds[le * 392 + 128 + f]);
                float wc = bf2f(dlds[le * 392 + 256 + f]);
                qa += x0 * wa;
                float xb = x1 * wb;
                float xc = x2 * wc;
                m0a += xb * cdir.x + xc * u0;
                m1a += xb * cdir.y + xc * u1;
                m2a += xb * cdir.z + xc * u2;
            }
        }
    }
    // ---- merge halves and commit
    if (h == 1) {
        pm[0 * 128 + f] = qa;
        pm[1 * 128 + f] = m0a;
        pm[2 * 128 + f] = m1a;
        pm[3 * 128 + f] = m2a;
    }
    __syncthreads();
    if (h == 0) {
        qa  += pm[0 * 128 + f];
        m0a += pm[1 * 128 + f];
        m1a += pm[2 * 128 + f];
        m2a += pm[3 * 128 + f];
        float qn = q[i * 128 + f] + qa;
        q[i * 128 + f] = qn;
        q_bf[i * 128 + f] = f2bf(qn);
        float mn0 = mu[(i * 3 + 0) * 128 + f] + m0a;
        float mn1 = mu[(i * 3 + 1) * 128 + f] + m1a;
        float mn2 = mu[(i * 3 + 2) * 128 + f] + m2a;
        mu[(i * 3 + 0) * 128 + f] = mn0;
        mu[(i * 3 + 1) * 128 + f] = mn1;
        mu[(i * 3 + 2) * 128 + f] = mn2;
        mu_bfB[(i * 3 + 0) * 128 + f] = f2bf(mn0);
        mu_bfB[(i * 3 + 1) * 128 + f] = f2bf(mn1);
        mu_bfB[(i * 3 + 2) * 128 + f] = f2bf(mn2);
    }
}

// ---------------- K3 (MFMA): fused mixv + mix2 + next-block x-MLP, 512 threads ----------------
// 8 waves split every N dimension twice as fine as the 256-thread version:
// A: 24 MFMA/wave, B1: 8, B2: 12, X1: 4, X2: 12. 16 waves/CU at 2 blocks/CU.
__global__ __launch_bounds__(512, 4) void k_mixx(const short* __restrict__ mu_bfB,
                                                 const short* __restrict__ Wvt,   // [256][128]
                                                 const short* __restrict__ q_bf_ro,
                                                 const short* __restrict__ W1t,   // [128][256]
                                                 const short* __restrict__ W2t,   // [384][128]
                                                 const float* __restrict__ b1,
                                                 const float* __restrict__ b2,
                                                 float* __restrict__ q,
                                                 float* __restrict__ mu,
                                                 short* __restrict__ q_bf,
                                                 short* __restrict__ mu_bfA,
                                                 const short* __restrict__ xW1t,  // [128][128]
                                                 const short* __restrict__ xW2t,  // [384][128]
                                                 const float* __restrict__ xb1,
                                                 const float* __restrict__ xb2,
                                                 unsigned char* __restrict__ x_fp8,
                                                 int do_x) {
    __shared__ short Vv[48 * 136];
    __shared__ short Vw[48 * 136];
    __shared__ __align__(16) short vnb[16 * 136];
    __shared__ short sb[16 * 128];
    __shared__ __align__(16) short hs[16 * 128];
    __shared__ __align__(16) short qs[16 * 128];
    int t = threadIdx.x;
    int wv = t >> 6, lane = t & 63, quad = lane >> 4, l16 = lane & 15;
    int a0 = blockIdx.x * 16;

    // ---- stage A: mu @ Wv (M=48, N=256, K=128); wave wv: cols [wv*32, wv*32+32) ----
    {
        floatx4 acc[3][2];
        #pragma unroll
        for (int mt = 0; mt < 3; ++mt)
            #pragma unroll
            for (int nt = 0; nt < 2; ++nt) acc[mt][nt] = {0.f, 0.f, 0.f, 0.f};
        #pragma unroll
        for (int kk = 0; kk < 4; ++kk) {
            short8 a[3];
            #pragma unroll
            for (int mt = 0; mt < 3; ++mt)
                a[mt] = *(const short8*)(mu_bfB + (a0 * 3 + mt * 16 + l16) * 128 + kk * 32 + quad * 8);
            #pragma unroll
            for (int nt = 0; nt < 2; ++nt) {
                short8 b = *(const short8*)(Wvt + (wv * 32 + nt * 16 + l16) * 128 + kk * 32 + quad * 8);
                #pragma unroll
                for (int mt = 0; mt < 3; ++mt)
                    acc[mt][nt] = __builtin_amdgcn_mfma_f32_16x16x32_bf16(a[mt], b, acc[mt][nt], 0, 0, 0);
            }
        }
        #pragma unroll
        for (int mt = 0; mt < 3; ++mt)
            #pragma unroll
            for (int nt = 0; nt < 2; ++nt)
                #pragma unroll
                for (int r = 0; r < 4; ++r) {
                    int row = mt * 16 + quad * 4 + r;
                    int col = wv * 32 + nt * 16 + l16;
                    short v = f2bf(acc[mt][nt][r]);
                    if (col < 128) Vv[row * 136 + col] = v;
                    else           Vw[row * 136 + col - 128] = v;
                }
    }
    __syncthreads();
    // ---- vn, s (2048 items over 512 threads) ----
    #pragma unroll
    for (int k = 0; k < 4; ++k) {
        int idx = k * 512 + t;
        int a = idx >> 7, c = idx & 127;
        float v0 = bf2f(Vv[(a * 3 + 0) * 136 + c]);
        float v1 = bf2f(Vv[(a * 3 + 1) * 136 + c]);
        float v2 = bf2f(Vv[(a * 3 + 2) * 136 + c]);
        float w0 = bf2f(Vw[(a * 3 + 0) * 136 + c]);
        float w1 = bf2f(Vw[(a * 3 + 1) * 136 + c]);
        float w2 = bf2f(Vw[(a * 3 + 2) * 136 + c]);
        vnb[a * 136 + c] = f2bf(sqrtf(v0 * v0 + v1 * v1 + v2 * v2 + 1e-8f));
        sb[a * 128 + c]  = f2bf(v0 * w0 + v1 * w1 + v2 * w2);
    }
    __syncthreads();
    // ---- stage B1: h = silu([q|vn] @ W1 + b1), K=256; wave wv: cols [wv*16,+16) ----
    {
        floatx4 acc0 = {0.f, 0.f, 0.f, 0.f};
        #pragma unroll
        for (int kk = 0; kk < 8; ++kk) {
            short8 a;
            if (kk < 4)
                a = *(const short8*)(q_bf_ro + (a0 + l16) * 128 + kk * 32 + quad * 8);
            else
                a = *(const short8*)(vnb + l16 * 136 + (kk - 4) * 32 + quad * 8);
            short8 b0 = *(const short8*)(W1t + (wv * 16 + l16) * 256 + kk * 32 + quad * 8);
            acc0 = __builtin_amdgcn_mfma_f32_16x16x32_bf16(a, b0, acc0, 0, 0, 0);
        }
        int n0 = wv * 16 + l16;
        float bia0 = b1[n0];
        #pragma unroll
        for (int r = 0; r < 4; ++r) {
            int m = quad * 4 + r;
            hs[m * 128 + n0] = f2bf(silu(acc0[r] + bia0));
        }
    }
    __syncthreads();
    // ---- stage B2: wave wv owns cols wv*16..+15 of dq, dmu, dqmu; in-register epilogue ----
    {
        floatx4 accB[3];
        #pragma unroll
        for (int c = 0; c < 3; ++c) accB[c] = {0.f, 0.f, 0.f, 0.f};
        #pragma unroll
        for (int kk = 0; kk < 4; ++kk) {
            short8 a = *(const short8*)(hs + l16 * 128 + kk * 32 + quad * 8);
            #pragma unroll
            for (int c = 0; c < 3; ++c) {
                int n = c * 128 + wv * 16 + l16;
                short8 b = *(const short8*)(W2t + n * 128 + kk * 32 + quad * 8);
                accB[c] = __builtin_amdgcn_mfma_f32_16x16x32_bf16(a, b, accB[c], 0, 0, 0);
            }
        }
        int co = wv * 16 + l16;
        float bq_  = b2[co];
        float bm_  = b2[128 + co];
        float bqm_ = b2[256 + co];
        #pragma unroll
        for (int r = 0; r < 4; ++r) {
            int m = quad * 4 + r;
            int ga = a0 + m;
            float dq   = accB[0][r] + bq_;
            float dmu  = accB[1][r] + bm_;
            float dqmu = accB[2][r] + bqm_;
            float sv = bf2f(sb[m * 128 + co]);
            float qn = q[ga * 128 + co] + dq + dqmu * sv;
            q[ga * 128 + co] = qn;
            short qnb = f2bf(qn);
            q_bf[ga * 128 + co] = qnb;
            qs[m * 128 + co] = qnb;
            #pragma unroll
            for (int d = 0; d < 3; ++d) {
                float mw = bf2f(Vw[(m * 3 + d) * 136 + co]);
                float mn = mu[(ga * 3 + d) * 128 + co] + dmu * mw;
                mu[(ga * 3 + d) * 128 + co] = mn;
                mu_bfA[(ga * 3 + d) * 128 + co] = f2bf(mn);
            }
        }
    }
    if (!do_x) return;
    __syncthreads();                  // qs complete; hs free (all B2 reads done)
    // ---- X-stage 1: h2 = silu(qs @ xW1 + xb1); wave wv: cols [wv*16,+16) ----
    {
        floatx4 acc0 = {0.f, 0.f, 0.f, 0.f};
        #pragma unroll
        for (int kk = 0; kk < 4; ++kk) {
            short8 a  = *(const short8*)(qs + l16 * 128 + kk * 32 + quad * 8);
            short8 b0 = *(const short8*)(xW1t + (wv * 16 + l16) * 128 + kk * 32 + quad * 8);
            acc0 = __builtin_amdgcn_mfma_f32_16x16x32_bf16(a, b0, acc0, 0, 0, 0);
        }
        int n0 = wv * 16 + l16;
        float bia0 = xb1[n0];
        #pragma unroll
        for (int r = 0; r < 4; ++r) {
            int m = quad * 4 + r;
            hs[m * 128 + n0] = f2bf(silu(acc0[r] + bia0));
        }
    }
    __syncthreads();
    // ---- X-stage 2: x = h2 @ xW2 + xb2 -> fp8; wave wv: cols [wv*48,+48) ----
    {
        floatx4 acc[3];
        #pragma unroll
        for (int jj = 0; jj < 3; ++jj) acc[jj] = {0.f, 0.f, 0.f, 0.f};
        #pragma unroll
        for (int kk = 0; kk < 4; ++kk) {
            short8 a = *(const short8*)(hs + l16 * 128 + kk * 32 + quad * 8);
            #pragma unroll
            for (int jj = 0; jj < 3; ++jj) {
                short8 b = *(const short8*)(xW2t + (wv * 48 + jj * 16 + l16) * 128 + kk * 32 + quad * 8);
                acc[jj] = __builtin_amdgcn_mfma_f32_16x16x32_bf16(a, b, acc[jj], 0, 0, 0);
            }
        }
        #pragma unroll
        for (int jj = 0; jj < 3; ++jj) {
            int n = wv * 48 + jj * 16 + l16;
            float bia = xb2[n];
            #pragma unroll
            for (int r = 0; r < 4; ++r) {
                int m = quad * 4 + r;
                x_fp8[(a0 + m) * 384 + n] = f2fp8(acc[jj][r] + bia);
            }
        }
    }
}

extern "C" void kernel_launch(void* const* d_in, const int* in_sizes, int n_in,
                              void* d_out, int out_size, void* d_ws, size_t ws_size,
                              hipStream_t stream) {
    const float* feat = (const float*)d_in[0];
    const float* dist = (const float*)d_in[1];
    const float* vec  = (const float*)d_in[2];
    const float* cut  = (const float*)d_in[3];
    const float* rbfs = (const float*)d_in[4];
    const float* fW   = (const float*)d_in[5];
    const float* fb   = (const float*)d_in[6];
    const float* iW1  = (const float*)d_in[7];
    const float* ib1  = (const float*)d_in[8];
    const float* iW2  = (const float*)d_in[9];
    const float* ib2  = (const float*)d_in[10];
    const float* mWv  = (const float*)d_in[11];
    const float* mW1  = (const float*)d_in[12];
    const float* mb1  = (const float*)d_in[13];
    const float* mW2  = (const float*)d_in[14];
    const float* mb2  = (const float*)d_in[15];
    const int* idx_i  = (const int*)d_in[16];
    const int* idx_j  = (const int*)d_in[17];

    float* q  = (float*)d_out;                 // 8192*128
    float* mu = (float*)d_out + NA * 128;      // 8192*3*128 (in-place across blocks)

    char* w = (char*)d_ws;
    unsigned char* x_fp8 = (unsigned char*)(w); // 3,145,728 B
    short* q_bf    = (short*)(w + 6291456);     // 2,097,152
    short* mu_bfA  = (short*)(w + 8388608);     // 6,291,456
    short* mu_bfB  = (short*)(w + 14680064);    // 6,291,456
    short* W1t     = (short*)(w + 20971520);    // 163,840   5x[128][128]
    short* W2t     = (short*)(w + 21135360);    // 491,520   5x[384][128]
    short* Wvt     = (short*)(w + 21626880);    // 327,680   5x[256][128]
    short* mW1t    = (short*)(w + 21954560);    // 327,680   5x[128][256]
    short* mW2t    = (short*)(w + 22282240);    // 491,520   5x[384][128]
    short* fWt     = (short*)(w + 22773760);    // 122,880   5x[384][32]
    int*   counts  = (int*)(w + 22896640);      // 32,768
    int*   cursor  = (int*)(w + 22929408);      // 32,768
    int*   offs    = (int*)(w + 22962176);      // 32,784 (NA+1, padded)
    int*   plist   = (int*)(w + 22994960);      // 262,144
    int*   jcsr    = (int*)(w + 23257104);      // 262,144
    float* cut_csr = (float*)(w + 23519248);    // 262,208 (NP+16)
    float4* dir_csr= (float4*)(w + 23781456);   // 1,048,576
    short* rbf_c   = (short*)(w + 24830032);    // 4,195,328 (NP+16)x32

    k_tconv<<<(5 * 16384 + 255) / 256, 256, 0, stream>>>(iW1, W1t, 128, 128, 5 * 16384);
    k_tconv<<<(5 * 49152 + 255) / 256, 256, 0, stream>>>(iW2, W2t, 128, 384, 5 * 49152);
    k_tconv<<<(5 * 32768 + 255) / 256, 256, 0, stream>>>(mWv, Wvt, 128, 256, 5 * 32768);
    k_tconv<<<(5 * 32768 + 255) / 256, 256, 0, stream>>>(mW1, mW1t, 256, 128, 5 * 32768);
    k_tconv<<<(5 * 49152 + 255) / 256, 256, 0, stream>>>(mW2, mW2t, 128, 384, 5 * 49152);
    k_tconv2<<<(5 * 12288 + 255) / 256, 256, 0, stream>>>(fW, fWt);
    k_init<<<NA * 384 / 256, 256, 0, stream>>>(feat, q, mu, q_bf, mu_bfA, counts, cursor);
    k_hist<<<NP / 256, 256, 0, stream>>>(idx_i, counts);
    k_scan<<<1, 1024, 0, stream>>>(counts, offs);
    k_fill<<<NP / 256, 256, 0, stream>>>(idx_i, offs, cursor, plist);
    k_prep<<<(NP + 16 + 255) / 256, 256, 0, stream>>>(plist, idx_j, cut, dist, vec, rbfs,
                                                      jcsr, cut_csr, dir_csr, rbf_c);

    k_x<<<NA / 16, 256, 0, stream>>>(q_bf, W1t, W2t, ib1, ib2, x_fp8);
    for (int b = 0; b < 5; ++b) {
        int bn = (b + 1) % 5;
        k_gather<<<NA, 256, 0, stream>>>(x_fp8, mu_bfA, rbf_c, fWt + b * 12288,
                                         fb + b * 384, jcsr, cut_csr, dir_csr,
                                         offs, q, mu, q_bf, mu_bfB);
        k_mixx<<<NA / 16, 512, 0, stream>>>(mu_bfB, Wvt + b * 32768, q_bf,
                                            mW1t + b * 32768, mW2t + b * 49152,
                                            mb1 + b * 128, mb2 + b * 384,
                                            q, mu, q_bf, mu_bfA,
                                            W1t + bn * 16384, W2t + bn * 49152,
                                            ib1 + bn * 128, ib2 + bn * 384,
                                            x_fp8, (b < 4) ? 1 : 0);
    }
}

// Round 8
// 442.089 us; speedup vs baseline: 1.2138x; 1.2138x over previous
//
#include <hip/hip_runtime.h>
#include <hip/hip_bf16.h>

#define NA 8192
#define NP 65536
#define WROW 1920

typedef short short8 __attribute__((ext_vector_type(8)));
typedef short short4v __attribute__((ext_vector_type(4)));
typedef float floatx4 __attribute__((ext_vector_type(4)));

static __device__ __forceinline__ short f2bf(float f) {
    union { float f; unsigned u; } v; v.f = f;
    unsigned r = v.u + 0x7FFF + ((v.u >> 16) & 1);
    return (short)(r >> 16);
}
static __device__ __forceinline__ float bf2f(short s) {
    union { unsigned u; float f; } v;
    v.u = ((unsigned)(unsigned short)s) << 16;
    return v.f;
}
static __device__ __forceinline__ unsigned char f2fp8(float f) {
    int p = __builtin_amdgcn_cvt_pk_fp8_f32(f, 0.f, 0, false);
    return (unsigned char)(p & 0xFF);
}
static __device__ __forceinline__ float fp82f(unsigned char b) {
    return __builtin_amdgcn_cvt_f32_fp8((int)b, 0);
}
static __device__ __forceinline__ float silu(float v) {
    return v / (1.f + __expf(-v));
}

// ---- swizzled weight convert: input W[b][K][N] row-major, output MFMA-fragment order:
// per b: tile (nt,kt) of 512 shorts; value at tile*512 + lane*8 + bb =
//   bf16(W[k = kt*32 + (lane>>4)*8 + bb][n = nt*16 + (lane&15)])
// Reader: one contiguous 1KB load per wave: *(short8*)(Wsw + tile*512 + lane*8).
__global__ __launch_bounds__(256) void k_tconv_sw(const float* __restrict__ W,
                                                  short* __restrict__ Wt,
                                                  int K, int N, int total) {
    int idx = blockIdx.x * 256 + threadIdx.x;
    if (idx >= total) return;
    int kn = K * N;
    int b = idx / kn;
    int r = idx - b * kn;
    int tile = r >> 9;
    int li = r & 511;
    int lane = li >> 3, bb = li & 7;
    int Kt = K >> 5;
    int nt = tile / Kt, kt = tile - nt * Kt;
    int k = kt * 32 + (lane >> 4) * 8 + bb;
    int n = nt * 16 + (lane & 15);
    Wt[idx] = f2bf(W[b * kn + k * N + n]);
}

// fWt swizzled: per b, 24 tiles (nt, kt=0, K padded 20->32).
__global__ __launch_bounds__(256) void k_tconv2(const float* __restrict__ fW,
                                                short* __restrict__ fWt) {
    int idx = blockIdx.x * 256 + threadIdx.x;   // 0..5*12288-1
    if (idx >= 5 * 12288) return;
    int b = idx / 12288;
    int r = idx - b * 12288;
    int nt = r >> 9;
    int li = r & 511;
    int lane = li >> 3, bb = li & 7;
    int k = (lane >> 4) * 8 + bb;
    int n = nt * 16 + (lane & 15);
    fWt[idx] = (k < 20) ? f2bf(fW[k * WROW + b * 384 + n]) : (short)0;
}

// ---------------- init ----------------
__global__ __launch_bounds__(256) void k_init(const float* __restrict__ feat,
                                              float* __restrict__ q,
                                              float* __restrict__ mu,
                                              short* __restrict__ q_bf,
                                              short* __restrict__ mu_bfA,
                                              int* __restrict__ counts,
                                              int* __restrict__ cursor) {
    int idx = blockIdx.x * 256 + threadIdx.x;     // 0 .. NA*384-1
    if (idx < NA * 128) { float v = feat[idx]; q[idx] = v; q_bf[idx] = f2bf(v); }
    mu[idx] = 0.f;
    mu_bfA[idx] = 0;
    if (idx < NA) { counts[idx] = 0; cursor[idx] = 0; }
}

// ---------------- CSR build ----------------
__global__ __launch_bounds__(256) void k_hist(const int* __restrict__ idx_i,
                                              int* __restrict__ counts) {
    int p = blockIdx.x * 256 + threadIdx.x;
    if (p < NP) atomicAdd(&counts[idx_i[p]], 1);
}

__global__ __launch_bounds__(1024) void k_scan(const int* __restrict__ counts,
                                               int* __restrict__ offs) {
    __shared__ int sums[1024];
    int t = threadIdx.x;
    int local[8];
    int s = 0;
    #pragma unroll
    for (int k = 0; k < 8; ++k) { local[k] = s; s += counts[t * 8 + k]; }
    sums[t] = s;
    __syncthreads();
    for (int off = 1; off < 1024; off <<= 1) {
        int v = sums[t];
        int u = (t >= off) ? sums[t - off] : 0;
        __syncthreads();
        sums[t] = v + u;
        __syncthreads();
    }
    int base = (t > 0) ? sums[t - 1] : 0;
    #pragma unroll
    for (int k = 0; k < 8; ++k) offs[t * 8 + k] = base + local[k];
    if (t == 1023) offs[NA] = sums[1023];
}

__global__ __launch_bounds__(256) void k_fill(const int* __restrict__ idx_i,
                                              const int* __restrict__ offs,
                                              int* __restrict__ cursor,
                                              int* __restrict__ plist) {
    int p = blockIdx.x * 256 + threadIdx.x;
    if (p < NP) {
        int i = idx_i[p];
        int pos = atomicAdd(&cursor[i], 1);
        plist[offs[i] + pos] = p;
    }
}

// ---------------- prep: pre-gather per-pair data into CSR order ----------------
__global__ __launch_bounds__(256) void k_prep(const int* __restrict__ plist,
                                              const int* __restrict__ idx_j,
                                              const float* __restrict__ cut,
                                              const float* __restrict__ dist,
                                              const float* __restrict__ vec,
                                              const float* __restrict__ rbfs,
                                              int* __restrict__ jcsr,
                                              float* __restrict__ cut_csr,
                                              float4* __restrict__ dir_csr,
                                              short* __restrict__ rbf_c) {
    int e = blockIdx.x * 256 + threadIdx.x;
    if (e >= NP) {                       // zero-pad 16 extra rows for tile overrun
        if (e < NP + 16) {
            cut_csr[e] = 0.f;
            #pragma unroll
            for (int k = 0; k < 32; ++k) rbf_c[e * 32 + k] = 0;
        }
        return;
    }
    int p = plist[e];
    jcsr[e] = idx_j[p];
    float c = cut[p];
    cut_csr[e] = c;
    float invd = 1.f / dist[p];
    float4 d;
    d.x = vec[p * 3 + 0] * invd;
    d.y = vec[p * 3 + 1] * invd;
    d.z = vec[p * 3 + 2] * invd;
    d.w = 0.f;
    dir_csr[e] = d;
    #pragma unroll
    for (int k = 0; k < 20; ++k) rbf_c[e * 32 + k] = f2bf(rbfs[p * 20 + k] * c);
    #pragma unroll
    for (int k = 20; k < 32; ++k) rbf_c[e * 32 + k] = 0;
}

// ---------------- K1 (MFMA): x = silu(q@W1+b1)@W2+b2, fp8 out (block 0 only) ----------------
// q staged to LDS (coalesced); weights in swizzled layout (1KB/wave loads).
__global__ __launch_bounds__(256) void k_x(const short* __restrict__ q_bf,
                                           const short* __restrict__ W1sw,  // [8 nt][4 kt]
                                           const short* __restrict__ W2sw,  // [24 nt][4 kt]
                                           const float* __restrict__ b1,
                                           const float* __restrict__ b2,
                                           unsigned char* __restrict__ x_fp8) {
    __shared__ __align__(16) short qtile[16 * 136];
    __shared__ __align__(16) short hs[16 * 136];
    int t = threadIdx.x;
    int wv = t >> 6, lane = t & 63, quad = lane >> 4, l16 = lane & 15;
    int a0 = blockIdx.x * 16;

    #pragma unroll
    for (int it = 0; it < 2; ++it) {
        int c = it * 256 + t;                // 512 short4 chunks
        int row = c >> 5, col4 = c & 31;
        *(short4v*)(qtile + row * 136 + col4 * 4) =
            *(const short4v*)(q_bf + (a0 + row) * 128 + col4 * 4);
    }
    __syncthreads();

    floatx4 acc0 = {0.f, 0.f, 0.f, 0.f}, acc1 = {0.f, 0.f, 0.f, 0.f};
    #pragma unroll
    for (int kk = 0; kk < 4; ++kk) {
        short8 a  = *(const short8*)(qtile + l16 * 136 + kk * 32 + quad * 8);
        short8 b0 = *(const short8*)(W1sw + ((wv * 2 + 0) * 4 + kk) * 512 + lane * 8);
        short8 bq = *(const short8*)(W1sw + ((wv * 2 + 1) * 4 + kk) * 512 + lane * 8);
        acc0 = __builtin_amdgcn_mfma_f32_16x16x32_bf16(a, b0, acc0, 0, 0, 0);
        acc1 = __builtin_amdgcn_mfma_f32_16x16x32_bf16(a, bq, acc1, 0, 0, 0);
    }
    __syncthreads();
    {
        int n0 = wv * 32 + l16;
        float bia0 = b1[n0], bia1 = b1[n0 + 16];
        #pragma unroll
        for (int r = 0; r < 4; ++r) {
            int m = quad * 4 + r;
            hs[m * 136 + n0]      = f2bf(silu(acc0[r] + bia0));
            hs[m * 136 + n0 + 16] = f2bf(silu(acc1[r] + bia1));
        }
    }
    __syncthreads();
    floatx4 acc[6];
    #pragma unroll
    for (int jj = 0; jj < 6; ++jj) acc[jj] = {0.f, 0.f, 0.f, 0.f};
    #pragma unroll
    for (int kk = 0; kk < 4; ++kk) {
        short8 a = *(const short8*)(hs + l16 * 136 + kk * 32 + quad * 8);
        #pragma unroll
        for (int jj = 0; jj < 6; ++jj) {
            short8 b = *(const short8*)(W2sw + ((wv * 6 + jj) * 4 + kk) * 512 + lane * 8);
            acc[jj] = __builtin_amdgcn_mfma_f32_16x16x32_bf16(a, b, acc[jj], 0, 0, 0);
        }
    }
    #pragma unroll
    for (int jj = 0; jj < 6; ++jj) {
        int n = wv * 96 + jj * 16 + l16;
        float bia = b2[n];
        #pragma unroll
        for (int r = 0; r < 4; ++r) {
            int m = quad * 4 + r;
            x_fp8[(a0 + m) * 384 + n] = f2fp8(acc[jj][r] + bia);
        }
    }
}

// ---------------- K2: per-atom gather, 256 threads ----------------
// Phase 1: desc via MFMA, fWt in swizzled layout (6 coalesced 1KB loads/wave).
// Phase 2: half h walks its parity of pairs; partials merged via LDS.
__global__ __launch_bounds__(256, 6) void k_gather(const unsigned char* __restrict__ x_fp8,
                                                   const short* __restrict__ mu_bfA,
                                                   const short* __restrict__ rbf_c,
                                                   const short* __restrict__ fWt,   // swizzled [24 nt]
                                                   const float* __restrict__ fbp,   // fb + bo
                                                   const int* __restrict__ jcsr,
                                                   const float* __restrict__ cut_csr,
                                                   const float4* __restrict__ dir_csr,
                                                   const int* __restrict__ offs,
                                                   float* __restrict__ q,
                                                   float* __restrict__ mu,
                                                   short* __restrict__ q_bf,
                                                   short* __restrict__ mu_bfB) {
    __shared__ short dlds[16 * 392];
    __shared__ float pm[4 * 128];
    int i = blockIdx.x;
    int t = threadIdx.x;
    int h = t >> 7;                             // pair-parity half
    int f = t & 127;                            // feature column
    int wv = t >> 6, lane = t & 63, quad = lane >> 4, l16 = lane & 15;
    int start = offs[i], end = offs[i + 1];
    float qa = 0.f, m0a = 0.f, m1a = 0.f, m2a = 0.f;

    for (int e0 = start; e0 < end; e0 += 16) {
        if (e0 > start) __syncthreads();        // protect dlds reuse
        // ---- phase 1: descriptors for rows e0..e0+15
        short8 a = *(const short8*)(rbf_c + (e0 + l16) * 32 + quad * 8);
        float c0 = cut_csr[e0 + quad * 4 + 0];
        float c1 = cut_csr[e0 + quad * 4 + 1];
        float c2 = cut_csr[e0 + quad * 4 + 2];
        float c3 = cut_csr[e0 + quad * 4 + 3];
        #pragma unroll
        for (int nt = 0; nt < 6; ++nt) {
            int col = wv * 96 + nt * 16 + l16;
            short8 bfr = *(const short8*)(fWt + (wv * 6 + nt) * 512 + lane * 8);
            floatx4 z = {0.f, 0.f, 0.f, 0.f};
            floatx4 acc = __builtin_amdgcn_mfma_f32_16x16x32_bf16(a, bfr, z, 0, 0, 0);
            float fbv = fbp[col];
            dlds[(quad * 4 + 0) * 392 + col] = f2bf(acc[0] + fbv * c0);
            dlds[(quad * 4 + 1) * 392 + col] = f2bf(acc[1] + fbv * c1);
            dlds[(quad * 4 + 2) * 392 + col] = f2bf(acc[2] + fbv * c2);
            dlds[(quad * 4 + 3) * 392 + col] = f2bf(acc[3] + fbv * c3);
        }
        __syncthreads();
        // ---- phase 2: this half walks its parity of pairs, depth-1 prefetch
        int lim = (end < e0 + 16) ? end : (e0 + 16);
        int e = e0 + h;
        if (e < lim) {
            int jA = jcsr[e];
            float4 dirA = dir_csr[e];
            unsigned char aX0 = x_fp8[jA * 384 + f];
            unsigned char aX1 = x_fp8[jA * 384 + 128 + f];
            unsigned char aX2 = x_fp8[jA * 384 + 256 + f];
            short aU0 = mu_bfA[jA * 384 + f];
            short aU1 = mu_bfA[jA * 384 + 128 + f];
            short aU2 = mu_bfA[jA * 384 + 256 + f];
            for (; e < lim; e += 2) {
                float x0 = fp82f(aX0), x1 = fp82f(aX1), x2 = fp82f(aX2);
                float u0 = bf2f(aU0), u1 = bf2f(aU1), u2 = bf2f(aU2);
                float4 cdir = dirA;
                int en = e + 2;
                if (en < lim) {
                    int jn = jcsr[en];
                    dirA = dir_csr[en];
                    aX0 = x_fp8[jn * 384 + f];
                    aX1 = x_fp8[jn * 384 + 128 + f];
                    aX2 = x_fp8[jn * 384 + 256 + f];
                    aU0 = mu_bfA[jn * 384 + f];
                    aU1 = mu_bfA[jn * 384 + 128 + f];
                    aU2 = mu_bfA[jn * 384 + 256 + f];
                }
                int le = e - e0;
                float wa = bf2f(dlds[le * 392 + f]);
                float wb = bf2f(dlds[le * 392 + 128 + f]);
                float wc = bf2f(dlds[le * 392 + 256 + f]);
                qa += x0 * wa;
                float xb = x1 * wb;
                float xc = x2 * wc;
                m0a += xb * cdir.x + xc * u0;
                m1a += xb * cdir.y + xc * u1;
                m2a += xb * cdir.z + xc * u2;
            }
        }
    }
    // ---- merge halves and commit
    if (h == 1) {
        pm[0 * 128 + f] = qa;
        pm[1 * 128 + f] = m0a;
        pm[2 * 128 + f] = m1a;
        pm[3 * 128 + f] = m2a;
    }
    __syncthreads();
    if (h == 0) {
        qa  += pm[0 * 128 + f];
        m0a += pm[1 * 128 + f];
        m1a += pm[2 * 128 + f];
        m2a += pm[3 * 128 + f];
        float qn = q[i * 128 + f] + qa;
        q[i * 128 + f] = qn;
        q_bf[i * 128 + f] = f2bf(qn);
        float mn0 = mu[(i * 3 + 0) * 128 + f] + m0a;
        float mn1 = mu[(i * 3 + 1) * 128 + f] + m1a;
        float mn2 = mu[(i * 3 + 2) * 128 + f] + m2a;
        mu[(i * 3 + 0) * 128 + f] = mn0;
        mu[(i * 3 + 1) * 128 + f] = mn1;
        mu[(i * 3 + 2) * 128 + f] = mn2;
        mu_bfB[(i * 3 + 0) * 128 + f] = f2bf(mn0);
        mu_bfB[(i * 3 + 1) * 128 + f] = f2bf(mn1);
        mu_bfB[(i * 3 + 2) * 128 + f] = f2bf(mn2);
    }
}

// ---------------- K3 (MFMA): fused mixv + mix2 + next-block x-MLP, 512 threads ----------------
// All A-operands from LDS (staged coalesced, stride-136 rows), all B-operands
// from swizzled weights (one contiguous 1KB load per wave). hs aliases Vv;
// new-q lives in qtile. LDS ~52 KB -> 3 blocks/CU.
__global__ __launch_bounds__(512, 4) void k_mixx(const short* __restrict__ mu_bfB,
                                                 const short* __restrict__ Wvsw,   // [16 nt][4 kt]
                                                 const short* __restrict__ q_bf_ro,
                                                 const short* __restrict__ W1sw,   // [8 nt][8 kt]
                                                 const short* __restrict__ W2sw,   // [24 nt][4 kt]
                                                 const float* __restrict__ b1,
                                                 const float* __restrict__ b2,
                                                 float* __restrict__ q,
                                                 float* __restrict__ mu,
                                                 short* __restrict__ q_bf,
                                                 short* __restrict__ mu_bfA,
                                                 const short* __restrict__ xW1sw,  // [8 nt][4 kt]
                                                 const short* __restrict__ xW2sw,  // [24 nt][4 kt]
                                                 const float* __restrict__ xb1,
                                                 const float* __restrict__ xb2,
                                                 unsigned char* __restrict__ x_fp8,
                                                 int do_x) {
    __shared__ __align__(16) char smem[51968];
    short* ms    = (short*)(smem);            // [48][136] staged mu_bfB
    short* qtile = (short*)(smem + 13056);    // [16][136] staged q (then new q)
    short* Vv    = (short*)(smem + 17408);    // [48][136] muV
    short* hs    = (short*)(smem + 17408);    // [16][136] alias (Vv dead after vn/s)
    short* Vw    = (short*)(smem + 30464);    // [48][136] muW
    short* vnb   = (short*)(smem + 43520);    // [16][136]
    short* sb    = (short*)(smem + 47872);    // [16][128]
    int t = threadIdx.x;
    int wv = t >> 6, lane = t & 63, quad = lane >> 4, l16 = lane & 15;
    int a0 = blockIdx.x * 16;

    // ---- stage A-operands into LDS (coalesced short4 loads) ----
    #pragma unroll
    for (int it = 0; it < 3; ++it) {
        int c = it * 512 + t;                // 1536 short4 chunks = 48x128
        int row = c >> 5, col4 = c & 31;
        *(short4v*)(ms + row * 136 + col4 * 4) =
            *(const short4v*)(mu_bfB + (a0 * 3 + row) * 128 + col4 * 4);
    }
    {
        int row = t >> 5, col4 = t & 31;     // 512 chunks = 16x128
        *(short4v*)(qtile + row * 136 + col4 * 4) =
            *(const short4v*)(q_bf_ro + (a0 + row) * 128 + col4 * 4);
    }
    __syncthreads();

    // ---- stage A: mu @ Wv (M=48, N=256, K=128); wave wv: cols [wv*32, +32) ----
    {
        floatx4 acc[3][2];
        #pragma unroll
        for (int mt = 0; mt < 3; ++mt)
            #pragma unroll
            for (int nt = 0; nt < 2; ++nt) acc[mt][nt] = {0.f, 0.f, 0.f, 0.f};
        #pragma unroll
        for (int kk = 0; kk < 4; ++kk) {
            short8 a[3];
            #pragma unroll
            for (int mt = 0; mt < 3; ++mt)
                a[mt] = *(const short8*)(ms + (mt * 16 + l16) * 136 + kk * 32 + quad * 8);
            #pragma unroll
            for (int nt = 0; nt < 2; ++nt) {
                short8 b = *(const short8*)(Wvsw + ((wv * 2 + nt) * 4 + kk) * 512 + lane * 8);
                #pragma unroll
                for (int mt = 0; mt < 3; ++mt)
                    acc[mt][nt] = __builtin_amdgcn_mfma_f32_16x16x32_bf16(a[mt], b, acc[mt][nt], 0, 0, 0);
            }
        }
        __syncthreads();      // ms reads done before Vv/Vw writes (Vv region separate; barrier orders vs later hs alias use)
        #pragma unroll
        for (int mt = 0; mt < 3; ++mt)
            #pragma unroll
            for (int nt = 0; nt < 2; ++nt)
                #pragma unroll
                for (int r = 0; r < 4; ++r) {
                    int row = mt * 16 + quad * 4 + r;
                    int col = wv * 32 + nt * 16 + l16;
                    short v = f2bf(acc[mt][nt][r]);
                    if (col < 128) Vv[row * 136 + col] = v;
                    else           Vw[row * 136 + col - 128] = v;
                }
    }
    __syncthreads();
    // ---- vn, s (2048 items over 512 threads) ----
    #pragma unroll
    for (int k = 0; k < 4; ++k) {
        int idx = k * 512 + t;
        int a = idx >> 7, c = idx & 127;
        float v0 = bf2f(Vv[(a * 3 + 0) * 136 + c]);
        float v1 = bf2f(Vv[(a * 3 + 1) * 136 + c]);
        float v2 = bf2f(Vv[(a * 3 + 2) * 136 + c]);
        float w0 = bf2f(Vw[(a * 3 + 0) * 136 + c]);
        float w1 = bf2f(Vw[(a * 3 + 1) * 136 + c]);
        float w2 = bf2f(Vw[(a * 3 + 2) * 136 + c]);
        vnb[a * 136 + c] = f2bf(sqrtf(v0 * v0 + v1 * v1 + v2 * v2 + 1e-8f));
        sb[a * 128 + c]  = f2bf(v0 * w0 + v1 * w1 + v2 * w2);
    }
    __syncthreads();
    // ---- stage B1: h = silu([q|vn] @ W1 + b1), K=256; wave wv: cols [wv*16,+16) ----
    {
        floatx4 acc0 = {0.f, 0.f, 0.f, 0.f};
        #pragma unroll
        for (int kk = 0; kk < 8; ++kk) {
            short8 a;
            if (kk < 4)
                a = *(const short8*)(qtile + l16 * 136 + kk * 32 + quad * 8);
            else
                a = *(const short8*)(vnb + l16 * 136 + (kk - 4) * 32 + quad * 8);
            short8 b0 = *(const short8*)(W1sw + (wv * 8 + kk) * 512 + lane * 8);
            acc0 = __builtin_amdgcn_mfma_f32_16x16x32_bf16(a, b0, acc0, 0, 0, 0);
        }
        __syncthreads();      // Vv reads (vn/s) done; hs alias write safe
        int n0 = wv * 16 + l16;
        float bia0 = b1[n0];
        #pragma unroll
        for (int r = 0; r < 4; ++r) {
            int m = quad * 4 + r;
            hs[m * 136 + n0] = f2bf(silu(acc0[r] + bia0));
        }
    }
    __syncthreads();
    // ---- stage B2: wave wv owns cols wv*16..+15 of dq, dmu, dqmu; in-register epilogue ----
    {
        floatx4 accB[3];
        #pragma unroll
        for (int c = 0; c < 3; ++c) accB[c] = {0.f, 0.f, 0.f, 0.f};
        #pragma unroll
        for (int kk = 0; kk < 4; ++kk) {
            short8 a = *(const short8*)(hs + l16 * 136 + kk * 32 + quad * 8);
            #pragma unroll
            for (int c = 0; c < 3; ++c) {
                short8 b = *(const short8*)(W2sw + ((c * 8 + wv) * 4 + kk) * 512 + lane * 8);
                accB[c] = __builtin_amdgcn_mfma_f32_16x16x32_bf16(a, b, accB[c], 0, 0, 0);
            }
        }
        int co = wv * 16 + l16;
        float bq_  = b2[co];
        float bm_  = b2[128 + co];
        float bqm_ = b2[256 + co];
        #pragma unroll
        for (int r = 0; r < 4; ++r) {
            int m = quad * 4 + r;
            int ga = a0 + m;
            float dq   = accB[0][r] + bq_;
            float dmu  = accB[1][r] + bm_;
            float dqmu = accB[2][r] + bqm_;
            float sv = bf2f(sb[m * 128 + co]);
            float qn = q[ga * 128 + co] + dq + dqmu * sv;
            q[ga * 128 + co] = qn;
            short qnb = f2bf(qn);
            q_bf[ga * 128 + co] = qnb;
            qtile[m * 136 + co] = qnb;
            #pragma unroll
            for (int d = 0; d < 3; ++d) {
                float mw = bf2f(Vw[(m * 3 + d) * 136 + co]);
                float mn = mu[(ga * 3 + d) * 128 + co] + dmu * mw;
                mu[(ga * 3 + d) * 128 + co] = mn;
                mu_bfA[(ga * 3 + d) * 128 + co] = f2bf(mn);
            }
        }
    }
    if (!do_x) return;
    __syncthreads();                  // qtile (new q) complete; hs free
    // ---- X-stage 1: h2 = silu(q_new @ xW1 + xb1); wave wv: cols [wv*16,+16) ----
    {
        floatx4 acc0 = {0.f, 0.f, 0.f, 0.f};
        #pragma unroll
        for (int kk = 0; kk < 4; ++kk) {
            short8 a  = *(const short8*)(qtile + l16 * 136 + kk * 32 + quad * 8);
            short8 b0 = *(const short8*)(xW1sw + (wv * 4 + kk) * 512 + lane * 8);
            acc0 = __builtin_amdgcn_mfma_f32_16x16x32_bf16(a, b0, acc0, 0, 0, 0);
        }
        __syncthreads();             // all B2 hs reads long done; ordered hs rewrite
        int n0 = wv * 16 + l16;
        float bia0 = xb1[n0];
        #pragma unroll
        for (int r = 0; r < 4; ++r) {
            int m = quad * 4 + r;
            hs[m * 136 + n0] = f2bf(silu(acc0[r] + bia0));
        }
    }
    __syncthreads();
    // ---- X-stage 2: x = h2 @ xW2 + xb2 -> fp8; wave wv: cols [wv*48,+48) ----
    {
        floatx4 acc[3];
        #pragma unroll
        for (int jj = 0; jj < 3; ++jj) acc[jj] = {0.f, 0.f, 0.f, 0.f};
        #pragma unroll
        for (int kk = 0; kk < 4; ++kk) {
            short8 a = *(const short8*)(hs + l16 * 136 + kk * 32 + quad * 8);
            #pragma unroll
            for (int jj = 0; jj < 3; ++jj) {
                short8 b = *(const short8*)(xW2sw + ((wv * 3 + jj) * 4 + kk) * 512 + lane * 8);
                acc[jj] = __builtin_amdgcn_mfma_f32_16x16x32_bf16(a, b, acc[jj], 0, 0, 0);
            }
        }
        #pragma unroll
        for (int jj = 0; jj < 3; ++jj) {
            int n = wv * 48 + jj * 16 + l16;
            float bia = xb2[n];
            #pragma unroll
            for (int r = 0; r < 4; ++r) {
                int m = quad * 4 + r;
                x_fp8[(a0 + m) * 384 + n] = f2fp8(acc[jj][r] + bia);
            }
        }
    }
}

extern "C" void kernel_launch(void* const* d_in, const int* in_sizes, int n_in,
                              void* d_out, int out_size, void* d_ws, size_t ws_size,
                              hipStream_t stream) {
    const float* feat = (const float*)d_in[0];
    const float* dist = (const float*)d_in[1];
    const float* vec  = (const float*)d_in[2];
    const float* cut  = (const float*)d_in[3];
    const float* rbfs = (const float*)d_in[4];
    const float* fW   = (const float*)d_in[5];
    const float* fb   = (const float*)d_in[6];
    const float* iW1  = (const float*)d_in[7];
    const float* ib1  = (const float*)d_in[8];
    const float* iW2  = (const float*)d_in[9];
    const float* ib2  = (const float*)d_in[10];
    const float* mWv  = (const float*)d_in[11];
    const float* mW1  = (const float*)d_in[12];
    const float* mb1  = (const float*)d_in[13];
    const float* mW2  = (const float*)d_in[14];
    const float* mb2  = (const float*)d_in[15];
    const int* idx_i  = (const int*)d_in[16];
    const int* idx_j  = (const int*)d_in[17];

    float* q  = (float*)d_out;                 // 8192*128
    float* mu = (float*)d_out + NA * 128;      // 8192*3*128 (in-place across blocks)

    char* w = (char*)d_ws;
    unsigned char* x_fp8 = (unsigned char*)(w); // 3,145,728 B
    short* q_bf    = (short*)(w + 6291456);     // 2,097,152
    short* mu_bfA  = (short*)(w + 8388608);     // 6,291,456
    short* mu_bfB  = (short*)(w + 14680064);    // 6,291,456
    short* W1t     = (short*)(w + 20971520);    // 163,840   5x[128][128] swizzled
    short* W2t     = (short*)(w + 21135360);    // 491,520   5x[384][128] swizzled
    short* Wvt     = (short*)(w + 21626880);    // 327,680   5x[256][128] swizzled
    short* mW1t    = (short*)(w + 21954560);    // 327,680   5x[128K][256N]->wait layout: mW1 is [256K][128N]
    short* mW2t    = (short*)(w + 22282240);    // 491,520   5x[384][128] swizzled
    short* fWt     = (short*)(w + 22773760);    // 122,880   5x 24 tiles swizzled
    int*   counts  = (int*)(w + 22896640);      // 32,768
    int*   cursor  = (int*)(w + 22929408);      // 32,768
    int*   offs    = (int*)(w + 22962176);      // 32,784 (NA+1, padded)
    int*   plist   = (int*)(w + 22994960);      // 262,144
    int*   jcsr    = (int*)(w + 23257104);      // 262,144
    float* cut_csr = (float*)(w + 23519248);    // 262,208 (NP+16)
    float4* dir_csr= (float4*)(w + 23781456);   // 1,048,576
    short* rbf_c   = (short*)(w + 24830032);    // 4,195,328 (NP+16)x32

    // swizzled weight prep (K,N per reference layouts: W[b][K][N])
    k_tconv_sw<<<(5 * 16384 + 255) / 256, 256, 0, stream>>>(iW1, W1t, 128, 128, 5 * 16384);
    k_tconv_sw<<<(5 * 49152 + 255) / 256, 256, 0, stream>>>(iW2, W2t, 128, 384, 5 * 49152);
    k_tconv_sw<<<(5 * 32768 + 255) / 256, 256, 0, stream>>>(mWv, Wvt, 128, 256, 5 * 32768);
    k_tconv_sw<<<(5 * 32768 + 255) / 256, 256, 0, stream>>>(mW1, mW1t, 256, 128, 5 * 32768);
    k_tconv_sw<<<(5 * 49152 + 255) / 256, 256, 0, stream>>>(mW2, mW2t, 128, 384, 5 * 49152);
    k_tconv2<<<(5 * 12288 + 255) / 256, 256, 0, stream>>>(fW, fWt);
    k_init<<<NA * 384 / 256, 256, 0, stream>>>(feat, q, mu, q_bf, mu_bfA, counts, cursor);
    k_hist<<<NP / 256, 256, 0, stream>>>(idx_i, counts);
    k_scan<<<1, 1024, 0, stream>>>(counts, offs);
    k_fill<<<NP / 256, 256, 0, stream>>>(idx_i, offs, cursor, plist);
    k_prep<<<(NP + 16 + 255) / 256, 256, 0, stream>>>(plist, idx_j, cut, dist, vec, rbfs,
                                                      jcsr, cut_csr, dir_csr, rbf_c);

    k_x<<<NA / 16, 256, 0, stream>>>(q_bf, W1t, W2t, ib1, ib2, x_fp8);
    for (int b = 0; b < 5; ++b) {
        int bn = (b + 1) % 5;
        k_gather<<<NA, 256, 0, stream>>>(x_fp8, mu_bfA, rbf_c, fWt + b * 12288,
                                         fb + b * 384, jcsr, cut_csr, dir_csr,
                                         offs, q, mu, q_bf, mu_bfB);
        k_mixx<<<NA / 16, 512, 0, stream>>>(mu_bfB, Wvt + b * 32768, q_bf,
                                            mW1t + b * 32768, mW2t + b * 49152,
                                            mb1 + b * 128, mb2 + b * 384,
                                            q, mu, q_bf, mu_bfA,
                                            W1t + bn * 16384, W2t + bn * 49152,
                                            ib1 + bn * 128, ib2 + bn * 384,
                                            x_fp8, (b < 4) ? 1 : 0);
    }
}